// Round 5
// baseline (713.879 us; speedup 1.0000x reference)
//
#include <hip/hip_runtime.h>

typedef _Float16 f16;
typedef __fp16 hf2 __attribute__((ext_vector_type(2)));
typedef _Float16 f16x4 __attribute__((ext_vector_type(4)));
typedef _Float16 f16x8 __attribute__((ext_vector_type(8)));
typedef float f32x4 __attribute__((ext_vector_type(4)));

typedef const __attribute__((address_space(1))) unsigned int guint;
typedef __attribute__((address_space(3))) unsigned int luint;
__device__ __forceinline__ void gl_lds16(const void* g, void* l) {
    __builtin_amdgcn_global_load_lds((guint*)g, (luint*)l, 16, 0, 0);
}

// ---------------- K0: convert + transpose 5 weight matrices (512x512) to f16 ----------------
__global__ __launch_bounds__(256) void wconv(const float* w0, const float* w1, const float* w2,
                                             const float* w3, const float* w4, f16* dst) {
    const float* src;
    switch (blockIdx.z) { case 0: src = w0; break; case 1: src = w1; break;
                          case 2: src = w2; break; case 3: src = w3; break; default: src = w4; }
    __shared__ float tile[32][33];
    int k0 = blockIdx.x * 32, n0 = blockIdx.y * 32;
    int t = threadIdx.x;
    int r = t >> 3, c4 = (t & 7) * 4;
    float4 v = *(const float4*)(src + (k0 + r) * 512 + n0 + c4);
    tile[r][c4 + 0] = v.x; tile[r][c4 + 1] = v.y; tile[r][c4 + 2] = v.z; tile[r][c4 + 3] = v.w;
    __syncthreads();
    f16x4 o;
    o[0] = (f16)tile[c4 + 0][r]; o[1] = (f16)tile[c4 + 1][r];
    o[2] = (f16)tile[c4 + 2][r]; o[3] = (f16)tile[c4 + 3][r];
    *(f16x4*)(dst + (size_t)blockIdx.z * 262144 + (n0 + r) * 512 + k0 + c4) = o;
}

// ---------------- K1: 128x128 double-buffered LDS GEMM, BK=32, 4 waves 2x2 ----------------
// A16: A staged via global_load_lds (f16). !A16: A reg-staged fp32 -> cvt_pkrtz -> f16 ds_write.
// Both-sides XOR swizzle for 64B-row f16 tiles: phys_blk = logical_blk ^ ((row>>1)&3)
// -> per quarter-wave, (row&1, blk) covers 8 bank-groups x 2 lanes = conflict-free.
template <bool A16, bool RELU, bool O16>
__global__ __launch_bounds__(256) void gemm_lds(const void* __restrict__ Ap,
                                                const f16* __restrict__ Bt,
                                                const float* __restrict__ bias,
                                                void* __restrict__ Cp) {
    constexpr int ASZ = 8192;
    constexpr int BUF = 16384;
    __shared__ __align__(16) char smem[2 * BUF];

    // bijective XCD-chunk swizzle (nwg = 3072 divisible by 8); 4 N-tiles share an A-panel
    const int cpx = gridDim.x >> 3;
    const int orig = blockIdx.x;
    const int wgid = (orig & 7) * cpx + (orig >> 3);
    const int by = wgid & 3;
    const int bx = wgid >> 2;
    const int r0 = bx * 128, c0 = by * 128;

    const int t = threadIdx.x;
    const int j = t & 63, w = t >> 6;
    const int lr = j & 15, lq = j >> 4;
    const int wr = (w >> 1) * 64, wc = (w & 1) * 64;

    // staging: linear LDS dst, pre-swizzled global source chunk
    const int ldsT = w * 1024 + j * 16;
    const int sb = (j & 3) ^ ((j >> 3) & 3);
    const char* bSrc = (const char*)Bt + ((size_t)(c0 + w * 16 + (j >> 2)) * 512 + sb * 8) * 2;
    const char* aSrc16 = (const char*)Ap + ((size_t)(r0 + w * 16 + (j >> 2)) * 512 + sb * 8) * 2;
    // fp32 reg-staging: thread t covers row t>>1, 64B half (t&1)
    const char* aSrc32 = (const char*)Ap + ((size_t)(r0 + (t >> 1)) * 512 + (t & 1) * 16) * 4;
    const int awRow = t >> 1;
    const int awS = (awRow >> 1) & 3;
    const int awc = (t & 1) * 2;
    const int aw0 = awRow * 64 + ((awc ^ awS) << 4);
    const int aw1 = awRow * 64 + (((awc + 1) ^ awS) << 4);

    // fragment ds_read byte offsets (kk-independent)
    int aoff[4], boff[4];
#pragma unroll
    for (int m = 0; m < 4; m++) {
        int row = wr + m * 16 + lr;
        aoff[m] = row * 64 + ((lq ^ ((row >> 1) & 3)) << 4);
    }
#pragma unroll
    for (int nb = 0; nb < 4; nb++) {
        int row = wc + nb * 16 + lr;
        boff[nb] = ASZ + row * 64 + ((lq ^ ((row >> 1) & 3)) << 4);
    }

    f32x4 acc[4][4] = {};

#define STAGE_B(tk, buf)                                      \
    do {                                                      \
        const char* bs_ = bSrc + (size_t)(tk) * 64;           \
        char* bl_ = smem + (buf) * BUF + ASZ + ldsT;          \
        gl_lds16(bs_, bl_);                                   \
        gl_lds16(bs_ + 65536, bl_ + 4096);                    \
    } while (0)
#define STAGE_A16(tk, buf)                                    \
    do {                                                      \
        const char* as_ = aSrc16 + (size_t)(tk) * 64;         \
        char* al_ = smem + (buf) * BUF + ldsT;                \
        gl_lds16(as_, al_);                                   \
        gl_lds16(as_ + 65536, al_ + 4096);                    \
    } while (0)
#define LOAD_A32(tk, ar)                                      \
    do {                                                      \
        const char* p_ = aSrc32 + (size_t)(tk) * 128;         \
        ar[0] = *(const float4*)(p_);                         \
        ar[1] = *(const float4*)(p_ + 16);                    \
        ar[2] = *(const float4*)(p_ + 32);                    \
        ar[3] = *(const float4*)(p_ + 48);                    \
    } while (0)
#define WRITE_A32(ar, buf)                                    \
    do {                                                      \
        hf2 p0_ = __builtin_amdgcn_cvt_pkrtz(ar[0].x, ar[0].y); \
        hf2 p1_ = __builtin_amdgcn_cvt_pkrtz(ar[0].z, ar[0].w); \
        hf2 p2_ = __builtin_amdgcn_cvt_pkrtz(ar[1].x, ar[1].y); \
        hf2 p3_ = __builtin_amdgcn_cvt_pkrtz(ar[1].z, ar[1].w); \
        hf2 p4_ = __builtin_amdgcn_cvt_pkrtz(ar[2].x, ar[2].y); \
        hf2 p5_ = __builtin_amdgcn_cvt_pkrtz(ar[2].z, ar[2].w); \
        hf2 p6_ = __builtin_amdgcn_cvt_pkrtz(ar[3].x, ar[3].y); \
        hf2 p7_ = __builtin_amdgcn_cvt_pkrtz(ar[3].z, ar[3].w); \
        f16x8 h0_, h1_;                                       \
        h0_[0] = (f16)p0_[0]; h0_[1] = (f16)p0_[1]; h0_[2] = (f16)p1_[0]; h0_[3] = (f16)p1_[1]; \
        h0_[4] = (f16)p2_[0]; h0_[5] = (f16)p2_[1]; h0_[6] = (f16)p3_[0]; h0_[7] = (f16)p3_[1]; \
        h1_[0] = (f16)p4_[0]; h1_[1] = (f16)p4_[1]; h1_[2] = (f16)p5_[0]; h1_[3] = (f16)p5_[1]; \
        h1_[4] = (f16)p6_[0]; h1_[5] = (f16)p6_[1]; h1_[6] = (f16)p7_[0]; h1_[7] = (f16)p7_[1]; \
        char* base_ = smem + (buf) * BUF;                     \
        *(f16x8*)(base_ + aw0) = h0_;                         \
        *(f16x8*)(base_ + aw1) = h1_;                         \
    } while (0)
#define COMPUTE(buf)                                          \
    do {                                                      \
        const char* sb_ = smem + (buf) * BUF;                 \
        f16x8 av[4], bv[4];                                   \
        _Pragma("unroll")                                     \
        for (int m = 0; m < 4; m++) av[m] = *(const f16x8*)(sb_ + aoff[m]); \
        _Pragma("unroll")                                     \
        for (int nb = 0; nb < 4; nb++) bv[nb] = *(const f16x8*)(sb_ + boff[nb]); \
        _Pragma("unroll")                                     \
        for (int m = 0; m < 4; m++)                           \
            _Pragma("unroll")                                 \
            for (int nb = 0; nb < 4; nb++)                    \
                acc[m][nb] = __builtin_amdgcn_mfma_f32_16x16x32_f16(av[m], bv[nb], acc[m][nb], 0, 0, 0); \
    } while (0)

    if (A16) {
        STAGE_A16(0, 0);
        STAGE_B(0, 0);
        __syncthreads();
        int cur = 0;
#pragma unroll 1
        for (int tk = 0; tk < 16; ++tk) {
            if (tk < 15) { STAGE_A16(tk + 1, cur ^ 1); STAGE_B(tk + 1, cur ^ 1); }
            COMPUTE(cur);
            __syncthreads();
            cur ^= 1;
        }
    } else {
        float4 ar[4];
        LOAD_A32(0, ar);
        STAGE_B(0, 0);
        WRITE_A32(ar, 0);
        __syncthreads();
        int cur = 0;
#pragma unroll 1
        for (int tk = 0; tk < 16; ++tk) {
            float4 an[4];
            if (tk < 15) { LOAD_A32(tk + 1, an); STAGE_B(tk + 1, cur ^ 1); }
            COMPUTE(cur);
            if (tk < 15) WRITE_A32(an, cur ^ 1);
            __syncthreads();
            cur ^= 1;
        }
    }
#undef STAGE_B
#undef STAGE_A16
#undef LOAD_A32
#undef WRITE_A32
#undef COMPUTE

#pragma unroll
    for (int nb = 0; nb < 4; nb++) {
        int col = c0 + wc + nb * 16 + lr;
        float b = bias[col];
#pragma unroll
        for (int m = 0; m < 4; m++) {
#pragma unroll
            for (int r = 0; r < 4; r++) {
                float v = acc[m][nb][r] + b;
                if (RELU) v = fmaxf(v, 0.0f);
                size_t row = (size_t)(r0 + wr + m * 16 + lq * 4 + r);
                if (O16) ((f16*)Cp)[row * 512 + col] = (f16)v;
                else     ((float*)Cp)[row * 512 + col] = v;
            }
        }
    }
}

// ---------------- K2: attention per (b,h,n). 1 wave/block. ----------------
__global__ __launch_bounds__(64) void attn_kernel(const f16* __restrict__ q,
                                                  const f16* __restrict__ k,
                                                  const f16* __restrict__ v,
                                                  f16* __restrict__ out) {
    const int h = blockIdx.x, n = blockIdx.y, b = blockIdx.z;
    __shared__ f16 sQ[48 * 72];
    __shared__ f16 sK[48 * 72];
    __shared__ f16 sP[48 * 72];   // [q=48][p padded to 64]
    __shared__ f16 sVt[64 * 72];  // [d=64][p padded to 64]
    const int l = threadIdx.x, lr = l & 15, lq = l >> 4;
    const size_t rowstride = 256 * 512;
    const size_t base = ((size_t)(b * 48) * 256 + n) * 512 + h * 64;

    const int pr = l >> 3, pc = (l & 7) * 8;
#pragma unroll
    for (int pass = 0; pass < 6; pass++) {
        int row = pass * 8 + pr;
        size_t g = base + (size_t)row * rowstride + pc;
        f16x8 qv = *(const f16x8*)(q + g);
        f16x8 kv = *(const f16x8*)(k + g);
        f16x8 vv = *(const f16x8*)(v + g);
        *(f16x8*)&sQ[row * 72 + pc] = qv;
        *(f16x8*)&sK[row * 72 + pc] = kv;
#pragma unroll
        for (int j = 0; j < 8; j++) sVt[(pc + j) * 72 + row] = vv[j];  // transpose V
    }
    {
        f16x8 z = {};
        *(f16x8*)&sVt[l * 72 + 48] = z;
        *(f16x8*)&sVt[l * 72 + 56] = z;
        if (l < 48) { *(f16x8*)&sP[l * 72 + 48] = z; *(f16x8*)&sP[l * 72 + 56] = z; }
    }
    __syncthreads();

    f32x4 s[3][3] = {};
#pragma unroll
    for (int ks = 0; ks < 2; ks++) {
        f16x8 aq[3], bk[3];
#pragma unroll
        for (int m = 0; m < 3; m++)  aq[m] = *(const f16x8*)&sQ[(m * 16 + lr) * 72 + ks * 32 + lq * 8];
#pragma unroll
        for (int nb = 0; nb < 3; nb++) bk[nb] = *(const f16x8*)&sK[(nb * 16 + lr) * 72 + ks * 32 + lq * 8];
#pragma unroll
        for (int m = 0; m < 3; m++)
#pragma unroll
            for (int nb = 0; nb < 3; nb++)
                s[m][nb] = __builtin_amdgcn_mfma_f32_16x16x32_f16(aq[m], bk[nb], s[m][nb], 0, 0, 0);
    }

#pragma unroll
    for (int m = 0; m < 3; m++) {
#pragma unroll
        for (int r = 0; r < 4; r++) {
            float a0 = s[m][0][r] * 0.125f, a1 = s[m][1][r] * 0.125f, a2 = s[m][2][r] * 0.125f;
            float mx = fmaxf(a0, fmaxf(a1, a2));
#pragma unroll
            for (int d = 1; d < 16; d <<= 1) mx = fmaxf(mx, __shfl_xor(mx, d));
            float e0 = __expf(a0 - mx), e1 = __expf(a1 - mx), e2 = __expf(a2 - mx);
            float sm = e0 + e1 + e2;
#pragma unroll
            for (int d = 1; d < 16; d <<= 1) sm += __shfl_xor(sm, d);
            float inv = 1.0f / sm;
            int row = m * 16 + lq * 4 + r;
            sP[row * 72 + 0  + lr] = (f16)(e0 * inv);
            sP[row * 72 + 16 + lr] = (f16)(e1 * inv);
            sP[row * 72 + 32 + lr] = (f16)(e2 * inv);
        }
    }
    __syncthreads();

    f32x4 o[3][4] = {};
#pragma unroll
    for (int ks = 0; ks < 2; ks++) {
        f16x8 ap[3], bvv[4];
#pragma unroll
        for (int m = 0; m < 3; m++)  ap[m] = *(const f16x8*)&sP[(m * 16 + lr) * 72 + ks * 32 + lq * 8];
#pragma unroll
        for (int nb = 0; nb < 4; nb++) bvv[nb] = *(const f16x8*)&sVt[(nb * 16 + lr) * 72 + ks * 32 + lq * 8];
#pragma unroll
        for (int m = 0; m < 3; m++)
#pragma unroll
            for (int nb = 0; nb < 4; nb++)
                o[m][nb] = __builtin_amdgcn_mfma_f32_16x16x32_f16(ap[m], bvv[nb], o[m][nb], 0, 0, 0);
    }

#pragma unroll
    for (int m = 0; m < 3; m++)
#pragma unroll
        for (int nb = 0; nb < 4; nb++)
#pragma unroll
            for (int r = 0; r < 4; r++) {
                int row = m * 16 + lq * 4 + r;
                out[base + (size_t)row * rowstride + nb * 16 + lr] = (f16)o[m][nb][r];
            }
}

// ---------------- launch ----------------
extern "C" void kernel_launch(void* const* d_in, const int* in_sizes, int n_in,
                              void* d_out, int out_size, void* d_ws, size_t ws_size,
                              hipStream_t stream) {
    const float* X    = (const float*)d_in[0];
    const float* STEP = (const float*)d_in[1];
    const float* STEQ = (const float*)d_in[2];
    const float* Wq   = (const float*)d_in[3];
    const float* bq   = (const float*)d_in[4];
    const float* Wk   = (const float*)d_in[5];
    const float* bk   = (const float*)d_in[6];
    const float* Wv   = (const float*)d_in[7];
    const float* bv   = (const float*)d_in[8];
    const float* W1   = (const float*)d_in[9];
    const float* b1   = (const float*)d_in[10];
    const float* W2   = (const float*)d_in[11];
    const float* b2   = (const float*)d_in[12];
    float* out = (float*)d_out;

    const size_t MROWS = 98304;           // B*TQ*N = 8*48*256
    f16* ws  = (f16*)d_ws;
    f16* Wqt = ws;                        // 512*512 each
    f16* Wkt = ws + 262144;
    f16* Wvt = ws + 524288;
    f16* W1t = ws + 786432;
    f16* W2t = ws + 1048576;
    f16* qb  = ws + 1310720;              // MROWS*512 f16
    f16* kb  = qb + MROWS * 512;
    f16* vb  = kb + MROWS * 512;
    f16* attn = qb;                       // attention writes in-place over q
    f16* hb   = kb;                       // FFN hidden reuses k buffer

    wconv<<<dim3(16, 16, 5), 256, 0, stream>>>(Wq, Wk, Wv, W1, W2, ws);

    gemm_lds<false, true, true><<<3072, 256, 0, stream>>>(STEQ, Wqt, bq, qb);
    gemm_lds<false, true, true><<<3072, 256, 0, stream>>>(STEP, Wkt, bk, kb);
    gemm_lds<false, true, true><<<3072, 256, 0, stream>>>(X,    Wvt, bv, vb);

    attn_kernel<<<dim3(8, 256, 8), 64, 0, stream>>>(qb, kb, vb, attn);

    gemm_lds<true, true,  true ><<<3072, 256, 0, stream>>>(attn, W1t, b1, hb);
    gemm_lds<true, false, false><<<3072, 256, 0, stream>>>(hb,   W2t, b2, out);
}